// Round 8
// baseline (338.160 us; speedup 1.0000x reference)
//
#include <hip/hip_runtime.h>
#include <hip/hip_cooperative_groups.h>
#include <math.h>

namespace cg = cooperative_groups;

typedef unsigned int u32;
typedef unsigned long long u64;

// Problem constants
#define N_13 16224
#define N_26 64896
#define N_52 259584
#define N_TOT 340704
#define KSEL 1024
#define NBINS 8192
#define CAND 2048
#define NBLK 64
#define NTHR 1024
#define GSTRIDE (NBLK * NTHR)

// Workspace layout (bytes)
#define WS_HIST 0UL                 // u32[NBINS] = 32768
#define WS_STK  32768UL             // u32[4]: counter, bsel
#define WS_CAND 32784UL             // u64[CAND] = 16384
#define WS_GATH 49168UL             // u64[1024] = 8192
#define WS_BOX7 57360UL             // float[1024*7] = 28672
#define WS_X1   86032UL
#define WS_Y1   90128UL
#define WS_X2   94224UL
#define WS_Y2   98320UL
#define WS_AR   102416UL
#define WS_SUP  106512UL            // u32[1024]
#define WS_MASK 110608UL            // u64[1024*16] = 131072 (end 241680)

__device__ __forceinline__ float sigmoid_(float x) {
  return 1.0f / (1.0f + expf(-x));   // XLA logistic_expander form
}

__device__ __forceinline__ u32 fkey_(float f) {
  u32 u = __float_as_uint(f);
  return (u & 0x80000000u) ? ~u : (u | 0x80000000u);
}

// monotone coarse bin (gather predicate only, never in sort key)
__device__ __forceinline__ int binof_(float l0, float score) {
  if (score == -1.0f) return 0;
  int b = (int)floorf((l0 + 8.0f) * 512.0f);
  return b < 0 ? 0 : (b > NBINS-1 ? NBINS-1 : b);
}

template<int G2>
__device__ __forceinline__ void hist_item(const float* __restrict__ fp, int u,
                                          float thr, u32* lh) {
  int p = u % G2; int c = u / G2; int a = c % 3; int b = c / 3;
  float l0 = fp[(size_t)(b*255 + a*85) * G2 + p];
  float conf = sigmoid_(l0);
  float score = (conf > thr) ? conf : -1.0f;
  atomicAdd(&lh[binof_(l0, score)], 1u);
}

template<int G2, int OFF>
__device__ __forceinline__ void gather_item(const float* __restrict__ fp, int u,
                                            float thr, u32 bsel,
                                            u32* stk, u64* cand) {
  int p = u % G2; int c = u / G2; int a = c % 3; int b = c / 3;
  float l0 = fp[(size_t)(b*255 + a*85) * G2 + p];
  float conf = sigmoid_(l0);
  float score = (conf > thr) ? conf : -1.0f;
  int bin = binof_(l0, score);
  if ((u32)bin >= bsel) {
    u32 iref = (u32)(OFF + (b*G2 + p)*3 + a);
    u64 key = ((u64)fkey_(score) << 19) | (u64)(524287u - iref);  // (score desc, idx asc)
    u32 pos = atomicAdd(&stk[0], 1u);
    if (pos < (u32)CAND) cand[pos] = key;
  }
}

union SmemT {
  u32 lh[NBINS];                                               // hist build
  u32 wsum[16];                                                // pick
  u64 sk[CAND];                                                // rank
  struct { float x1[1024], y1[1024], x2[1024], y2[1024], ar[1024]; } mk;
  struct { u32 sm32[33280]; u32 sw[32]; } rs;                  // 1040 rows x 32 words
};

__global__ __launch_bounds__(NTHR) void fused_kernel(
    const float* __restrict__ f13, const float* __restrict__ f26,
    const float* __restrict__ f52, const float* __restrict__ thr_p,
    const float* __restrict__ case_p, const float* __restrict__ a13,
    const float* __restrict__ a26, const float* __restrict__ a52,
    float* __restrict__ out, char* __restrict__ ws) {
  __shared__ SmemT sm;
  cg::grid_group grid = cg::this_grid();

  u32* hist = (u32*)(ws + WS_HIST);
  u32* stk  = (u32*)(ws + WS_STK);
  u64* cand = (u64*)(ws + WS_CAND);
  u64* gath = (u64*)(ws + WS_GATH);
  float* box7 = (float*)(ws + WS_BOX7);
  float* bx1 = (float*)(ws + WS_X1);
  float* by1 = (float*)(ws + WS_Y1);
  float* bx2 = (float*)(ws + WS_X2);
  float* by2 = (float*)(ws + WS_Y2);
  float* bar = (float*)(ws + WS_AR);
  u32* bsup = (u32*)(ws + WS_SUP);
  u64* mask = (u64*)(ws + WS_MASK);

  const int tid = threadIdx.x;
  const int gtid = blockIdx.x * NTHR + tid;

  // ---- P0: zero globals; build per-block LDS histogram ----
  for (int i = tid; i < NBINS; i += NTHR) sm.lh[i] = 0u;
  __syncthreads();
  if (gtid < NBINS) hist[gtid] = 0u;
  if (gtid < 4) stk[gtid] = 0u;
  if (gtid < CAND) cand[gtid] = 0ull;
  {
    float thr = *thr_p;
    for (int u = gtid; u < N_13; u += GSTRIDE) hist_item<169 >(f13, u, thr, sm.lh);
    for (int u = gtid; u < N_26; u += GSTRIDE) hist_item<676 >(f26, u, thr, sm.lh);
    for (int u = gtid; u < N_52; u += GSTRIDE) hist_item<2704>(f52, u, thr, sm.lh);
  }
  __syncthreads();
  grid.sync();

  // ---- P1: merge LDS hists into global ----
  for (int i = tid; i < NBINS; i += NTHR) {
    u32 v = sm.lh[i];
    if (v) atomicAdd(&hist[i], v);
  }
  grid.sync();

  // ---- P2: pick threshold bin (block 0) ----
  if (blockIdx.x == 0) {
    u32 h[8]; u32 s = 0;
    #pragma unroll
    for (int d = 0; d < 8; ++d) { h[d] = hist[tid*8 + d]; s += h[d]; }
    u32 r = s;
    #pragma unroll
    for (int off = 1; off < 64; off <<= 1) {           // wave inclusive suffix sum
      u32 v = __shfl_down(r, off);
      if ((tid & 63) + off < 64) r += v;
    }
    if ((tid & 63) == 0) sm.wsum[tid >> 6] = r;
    __syncthreads();
    u32 add = 0;
    for (int w2 = (tid >> 6) + 1; w2 < 16; ++w2) add += sm.wsum[w2];
    u32 suf = r + add;                                 // suffix sum at tid
    if (suf >= (u32)KSEL && (suf - s) < (u32)KSEL) {   // unique winner chunk
      u32 cum = suf - s;
      int bsel = tid*8;
      for (int d = 7; d >= 0; --d) {
        cum += h[d];
        if (cum >= (u32)KSEL) { bsel = tid*8 + d; break; }
      }
      stk[1] = (u32)bsel;
    }
  }
  grid.sync();

  // ---- P3: gather candidates (bin >= bsel) ----
  {
    float thr = *thr_p;
    u32 bsel = stk[1];
    for (int u = gtid; u < N_13; u += GSTRIDE) gather_item<169 , 0          >(f13, u, thr, bsel, stk, cand);
    for (int u = gtid; u < N_26; u += GSTRIDE) gather_item<676 , N_13      >(f26, u, thr, bsel, stk, cand);
    for (int u = gtid; u < N_52; u += GSTRIDE) gather_item<2704, N_13+N_26 >(f52, u, thr, bsel, stk, cand);
  }
  grid.sync();

  // ---- P4: parallel rank-by-count (exact top-1024 sorted scatter) ----
  {
    for (int k = tid; k < CAND; k += NTHR) sm.sk[k] = cand[k];
    __syncthreads();
    int e = blockIdx.x * 32 + (tid >> 5);
    int sub = tid & 31;
    u64 mykey = sm.sk[e];
    u32 cnt = 0;
    for (int s = 0; s < 64; ++s) {
      int j = sub*64 + ((s + sub) & 63);   // swizzle: spread banks
      cnt += (sm.sk[j] > mykey) ? 1u : 0u;
    }
    #pragma unroll
    for (int off = 1; off < 32; off <<= 1) cnt += __shfl_xor(cnt, off);
    if (sub == 0 && cnt < (u32)KSEL) gath[cnt] = mykey;  // keys unique -> ranks unique
  }
  grid.sync();

  // ---- P5: decode 1024 boxes, one wave per box ----
  {
    int r = blockIdx.x * 16 + (tid >> 6);
    int lane = tid & 63;
    u64 key = gath[r];
    u32 idx = 524287u - ((u32)key & 0x7FFFFu);
    u32 sb = (u32)(key >> 19);
    sb = (sb & 0x80000000u) ? (sb & 0x7FFFFFFFu) : ~sb;
    float score = __uint_as_float(sb);
    float case_v = *case_p;

    const float* fp; const float* ap; u32 G, G2, off; float tt;
    if (idx < N_13)            { fp=f13; ap=a13; G=13; G2=169;  off=0;          tt=32.0f; }
    else if (idx < N_13+N_26)  { fp=f26; ap=a26; G=26; G2=676;  off=N_13;       tt=16.0f; }
    else                       { fp=f52; ap=a52; G=52; G2=2704; off=N_13+N_26;  tt=8.0f;  }
    u32 L = idx - off;
    u32 a = L % 3u; u32 q = L / 3u;
    u32 x = q % G; u32 rq = q / G; u32 y = rq % G; u32 b = rq / G;

    const float* base = fp + (size_t)(b*255u + a*85u) * G2 + y*G + x;
    float l0 = base[0];
    float conf = sigmoid_(l0);
    float l2 = base[(size_t)2*G2];
    float l3 = base[(size_t)3*G2];
    float l4 = base[(size_t)4*G2];
    float cy = ((float)y + l2) * tt / case_v;
    float cx = ((float)x + l2) * tt / case_v;   // reference quirk: both use ch 2
    float w = ap[2*a]     * expf(l3) / case_v;
    float h = ap[2*a + 1] * expf(l4) / case_v;

    // argmax over softmax(logits[5:85]) exactly like the reference
    bool v2ok = (lane < 16);
    float x1v = base[(size_t)(5 + lane) * G2];
    float x2v = v2ok ? base[(size_t)(5 + 64 + lane) * G2] : -INFINITY;
    float mx = fmaxf(x1v, x2v);
    #pragma unroll
    for (int o = 32; o > 0; o >>= 1) mx = fmaxf(mx, __shfl_xor(mx, o));
    float e1 = expf(x1v - mx);
    float e2 = v2ok ? expf(x2v - mx) : 0.0f;
    float ssum = e1 + e2;
    #pragma unroll
    for (int o = 32; o > 0; o >>= 1) ssum += __shfl_xor(ssum, o);
    float p1 = e1 / ssum;
    float p2 = v2ok ? (e2 / ssum) : -1.0f;
    float pm = p1; int ci = lane;
    if (p2 > pm) { pm = p2; ci = lane + 64; }
    #pragma unroll
    for (int o = 32; o > 0; o >>= 1) {
      float om = __shfl_xor(pm, o);
      int   oc = __shfl_xor(ci, o);
      if (om > pm || (om == pm && oc < ci)) { pm = om; ci = oc; }
    }

    if (lane == 0) {
      box7[r*7 + 0] = (float)b;
      box7[r*7 + 1] = conf;
      box7[r*7 + 2] = cx;
      box7[r*7 + 3] = cy;
      box7[r*7 + 4] = w;
      box7[r*7 + 5] = h;
      box7[r*7 + 6] = (float)ci;
      float hw = __fmul_rn(w, 0.5f);
      float hh = __fmul_rn(h, 0.5f);
      bx1[r] = __fsub_rn(cx, hw);
      bx2[r] = __fadd_rn(cx, hw);
      by1[r] = __fsub_rn(cy, hh);
      by2[r] = __fadd_rn(cy, hh);
      bar[r] = __fmul_rn(w, h);
      bsup[r] = (score <= 0.0f) ? 1u : 0u;
    }
  }
  grid.sync();

  // ---- P6: suppression bit-matrix (blocks 0..15) ----
  if (blockIdx.x < 16) {
    sm.mk.x1[tid] = bx1[tid]; sm.mk.y1[tid] = by1[tid];
    sm.mk.x2[tid] = bx2[tid]; sm.mk.y2[tid] = by2[tid];
    sm.mk.ar[tid] = bar[tid];
    __syncthreads();
    int P = blockIdx.x * NTHR + tid;
    int i = P >> 4, w = P & 15;
    float x1 = sm.mk.x1[i], y1 = sm.mk.y1[i];
    float x2 = sm.mk.x2[i], y2 = sm.mk.y2[i], ar = sm.mk.ar[i];
    u64 m = 0;
    int j0 = w << 6;
    for (int b = 0; b < 64; ++b) {
      int j = j0 + b;
      float iw = fmaxf(__fsub_rn(fminf(sm.mk.x2[j], x2), fmaxf(sm.mk.x1[j], x1)), 0.0f);
      float ih = fmaxf(__fsub_rn(fminf(sm.mk.y2[j], y2), fmaxf(sm.mk.y1[j], y1)), 0.0f);
      float inter = __fmul_rn(iw, ih);
      float den = __fadd_rn(__fsub_rn(__fadd_rn(ar, sm.mk.ar[j]), inter), 1e-9f);
      float iou = inter / den;                 // IEEE divide, both sides
      if (iou > 0.5f && j > i) m |= (1ull << b);
    }
    mask[i*16 + w] = m;
  }
  grid.sync();

  // ---- P7: serial resolve via readlane chain + output (block 0) ----
  if (blockIdx.x == 0) {
    u64* smask = (u64*)sm.rs.sm32;
    for (int k = tid; k < 16384; k += NTHR) smask[k] = mask[k];
    if (tid < 256) smask[16384 + tid] = 0ull;      // pad rows 1024..1039
    if (tid < 32) sm.rs.sw[tid] = 0u;
    __syncthreads();
    if (bsup[tid]) atomicOr(&sm.rs.sw[tid >> 5], 1u << (tid & 31));
    __syncthreads();
    if (tid < 64) {
      int lane = tid;
      bool act = lane < 32;
      u32 supp = act ? sm.rs.sw[lane] : 0u;
      u32 cur[8], nxt[8];
      #pragma unroll
      for (int k = 0; k < 8; ++k) cur[k] = act ? sm.rs.sm32[k*32 + lane] : 0u;
      for (int blk = 0; blk < 128; ++blk) {
        #pragma unroll
        for (int k = 0; k < 8; ++k)                 // prefetch next 8 rows
          nxt[k] = act ? sm.rs.sm32[(blk*8 + 8 + k)*32 + lane] : 0u;
        #pragma unroll
        for (int k = 0; k < 8; ++k) {
          int i = blk*8 + k;
          u32 swd = (u32)__builtin_amdgcn_readlane((int)supp, i >> 5);
          if (!((swd >> (i & 31)) & 1u)) supp |= cur[k];
        }
        #pragma unroll
        for (int k = 0; k < 8; ++k) cur[k] = nxt[k];
      }
      if (act) sm.rs.sw[lane] = supp;
    }
    __syncthreads();
    u32 keep = !((sm.rs.sw[tid >> 5] >> (tid & 31)) & 1u);
    #pragma unroll
    for (int c = 0; c < 7; ++c) {
      float v = box7[tid*7 + c];
      out[tid*7 + c] = keep ? v : 0.0f;
    }
  }
}

extern "C" void kernel_launch(void* const* d_in, const int* in_sizes, int n_in,
                              void* d_out, int out_size, void* d_ws, size_t ws_size,
                              hipStream_t stream) {
  const float* f13 = (const float*)d_in[0];
  const float* f26 = (const float*)d_in[1];
  const float* f52 = (const float*)d_in[2];
  const float* thr = (const float*)d_in[3];
  const float* cas = (const float*)d_in[4];
  const float* a13 = (const float*)d_in[5];
  const float* a26 = (const float*)d_in[6];
  const float* a52 = (const float*)d_in[7];
  float* out = (float*)d_out;
  char* ws = (char*)d_ws;

  void* args[] = { (void*)&f13, (void*)&f26, (void*)&f52, (void*)&thr,
                   (void*)&cas, (void*)&a13, (void*)&a26, (void*)&a52,
                   (void*)&out, (void*)&ws };
  hipLaunchCooperativeKernel((void*)fused_kernel, dim3(NBLK), dim3(NTHR),
                             args, 0, stream);
}